// Round 1
// baseline (281.947 us; speedup 1.0000x reference)
//
#include <hip/hip_runtime.h>
#include <hip/hip_bf16.h>

// Problem constants (fixed by the reference)
#define NROWS 262144
#define KVOL  27
#define CIN   32
#define COUT  64
#define BN_EPS 1e-5f

using bf16x8 = __attribute__((ext_vector_type(8))) short;  // 8 bf16 = 4 VGPRs (MFMA A/B frag)
using f32x4  = __attribute__((ext_vector_type(4))) float;  // MFMA C/D frag

// ---- workspace layout (bytes) ----
// x_bf16 : N*32*2        = 16 MiB   @ 0
// Wfrag  : 27*4*64*8*2   = 110592 B @ 16 MiB
// gacc   : 128 f32 (sum[64], sumsq[64])        @ 16 MiB + 128 KiB
// ss     : 128 f32 (scale[64], shift[64])      @ 16 MiB + 128 KiB + 512
// y_bf16 : N*64*2        = 32 MiB   @ 17 MiB
// total ~49 MiB
#define OFF_XB  0ull
#define OFF_WF  (16ull<<20)
#define OFF_ACC ((16ull<<20) + (128ull<<10))
#define OFF_SS  ((16ull<<20) + (128ull<<10) + 512ull)
#define OFF_Y   (17ull<<20)

__device__ __forceinline__ unsigned short f2bf(float f) {
    __hip_bfloat16 h = __float2bfloat16(f);
    return __builtin_bit_cast(unsigned short, h);
}

// ---- kernel 0: x f32 -> bf16 (vectorized) ----
__global__ void k_cvt_x(const float4* __restrict__ x4, ushort4* __restrict__ xb4) {
    int i = blockIdx.x * 256 + threadIdx.x;   // grid exactly covers N*32/4
    float4 v = x4[i];
    ushort4 o;
    o.x = f2bf(v.x); o.y = f2bf(v.y); o.z = f2bf(v.z); o.w = f2bf(v.w);
    xb4[i] = o;
}

// ---- kernel 0b: repack W[27][32][64] f32 -> B-fragment-ordered bf16, zero accumulators ----
// Wfrag[kk][t][lane][j] = W[kk][(lane>>4)*8 + j][t*16 + (lane&15)]
__global__ void k_repack_w(const float* __restrict__ W, __hip_bfloat16* __restrict__ wf,
                           float* __restrict__ gacc) {
    int kk = blockIdx.x;            // 0..26
    int tid = threadIdx.x;          // 0..255
    int t = tid >> 6, l = tid & 63;
    int c0 = (l >> 4) * 8;
    int co = t * 16 + (l & 15);
    __hip_bfloat16* dst = wf + ((size_t)(kk * 4 + t) * 64 + l) * 8;
    #pragma unroll
    for (int j = 0; j < 8; ++j) {
        float v = W[(size_t)(kk * CIN + c0 + j) * COUT + co];
        dst[j] = __float2bfloat16(v);
    }
    if (kk == 0 && tid < 128) gacc[tid] = 0.0f;   // zero sum/sumsq (ws is poisoned 0xAA)
}

// ---- kernel 1: gather + MFMA GEMM -> y(bf16), per-channel sum/sumsq ----
// Block = 256 threads = 4 waves. Wave handles 64 rows x 64 cols (4x4 16x16 frags).
__global__ void __launch_bounds__(256)
k_gemm(const __hip_bfloat16* __restrict__ xb, const __hip_bfloat16* __restrict__ wf,
       const int* __restrict__ idx, __hip_bfloat16* __restrict__ y,
       float* __restrict__ gacc) {
    __shared__ float ssum[4][64];
    __shared__ float ssq[4][64];

    const int tid  = threadIdx.x;
    const int w    = tid >> 6;
    const int l    = tid & 63;
    const int lrow = l & 15;      // A row / D col within frag
    const int lk8  = l >> 4;      // k-group (A/B) and row-group (D)
    const int rb   = blockIdx.x * 256 + w * 64;

    f32x4 acc[4][4] = {};
    const bf16x8* wf8 = (const bf16x8*)wf;

    for (int kk = 0; kk < KVOL; ++kk) {
        int id[4];
        #pragma unroll
        for (int m = 0; m < 4; ++m)
            id[m] = idx[(rb + m * 16 + lrow) * KVOL + kk];   // L1-resident after first k

        bf16x8 a[4];
        #pragma unroll
        for (int m = 0; m < 4; ++m)   // gathered A-frag: one dwordx4 per lane, no LDS
            a[m] = *(const bf16x8*)(xb + (size_t)id[m] * CIN + lk8 * 8);

        bf16x8 bq[4];
        #pragma unroll
        for (int t = 0; t < 4; ++t)
            bq[t] = wf8[(kk * 4 + t) * 64 + l];

        #pragma unroll
        for (int m = 0; m < 4; ++m)
            #pragma unroll
            for (int t = 0; t < 4; ++t)
                acc[m][t] = __builtin_amdgcn_mfma_f32_16x16x32_bf16(a[m], bq[t], acc[m][t], 0, 0, 0);
    }

    // epilogue: store y (bf16) + lane-local channel sums
    float s[4] = {0, 0, 0, 0}, sq[4] = {0, 0, 0, 0};
    #pragma unroll
    for (int m = 0; m < 4; ++m) {
        #pragma unroll
        for (int r = 0; r < 4; ++r) {
            int row = rb + m * 16 + lk8 * 4 + r;   // D: row=(l>>4)*4+reg, col=l&15
            #pragma unroll
            for (int t = 0; t < 4; ++t) {
                float v = acc[m][t][r];
                y[(size_t)row * COUT + t * 16 + lrow] = __float2bfloat16(v);
                s[t] += v;
                sq[t] += v * v;
            }
        }
    }
    // lanes {l, l+16, l+32, l+48} share a channel -> butterfly over bits 4,5
    #pragma unroll
    for (int t = 0; t < 4; ++t) {
        s[t]  += __shfl_xor(s[t], 16, 64);  s[t]  += __shfl_xor(s[t], 32, 64);
        sq[t] += __shfl_xor(sq[t], 16, 64); sq[t] += __shfl_xor(sq[t], 32, 64);
    }
    if (l < 16) {
        #pragma unroll
        for (int t = 0; t < 4; ++t) { ssum[w][t * 16 + l] = s[t]; ssq[w][t * 16 + l] = sq[t]; }
    }
    __syncthreads();
    if (tid < 64) {
        float ts = 0, tq = 0;
        #pragma unroll
        for (int ww = 0; ww < 4; ++ww) { ts += ssum[ww][tid]; tq += ssq[ww][tid]; }
        atomicAdd(&gacc[tid], ts);
        atomicAdd(&gacc[64 + tid], tq);
    }
}

// ---- kernel 1.5: per-channel scale/shift.  Note conv bias b cancels under BN. ----
__global__ void k_stats(const float* __restrict__ gacc, const float* __restrict__ gamma,
                        const float* __restrict__ beta, float* __restrict__ ss) {
    int c = threadIdx.x;  // 64
    float inv_n = 1.0f / (float)NROWS;
    float mean = gacc[c] * inv_n;
    float var  = gacc[64 + c] * inv_n - mean * mean;
    float rstd = rsqrtf(var + BN_EPS);
    float sc = gamma[c] * rstd;
    ss[c] = sc;
    ss[64 + c] = beta[c] - mean * sc;
}

// ---- kernel 2: out = relu(y * scale + shift), vectorized 8 bf16 in / 2x float4 out ----
__global__ void k_apply(const uint4* __restrict__ y8, const float* __restrict__ ss,
                        float* __restrict__ out) {
    const int nchunk = NROWS * COUT / 8;
    int i0 = blockIdx.x * blockDim.x + threadIdx.x;
    int c0 = (i0 * 8) & 63;           // stride (2048*256*8) % 64 == 0 -> cols fixed per thread
    float sc[8], sh[8];
    #pragma unroll
    for (int j = 0; j < 8; ++j) { sc[j] = ss[c0 + j]; sh[j] = ss[64 + c0 + j]; }
    for (int i = i0; i < nchunk; i += gridDim.x * blockDim.x) {
        uint4 v = y8[i];
        const unsigned short* p = (const unsigned short*)&v;
        float r[8];
        #pragma unroll
        for (int j = 0; j < 8; ++j) {
            float f = __uint_as_float((unsigned)p[j] << 16);
            r[j] = fmaxf(0.0f, f * sc[j] + sh[j]);
        }
        float4* o = (float4*)(out + (size_t)i * 8);
        o[0] = make_float4(r[0], r[1], r[2], r[3]);
        o[1] = make_float4(r[4], r[5], r[6], r[7]);
    }
}

extern "C" void kernel_launch(void* const* d_in, const int* in_sizes, int n_in,
                              void* d_out, int out_size, void* d_ws, size_t ws_size,
                              hipStream_t stream) {
    const float* x     = (const float*)d_in[0];
    const float* W     = (const float*)d_in[1];
    // d_in[2] = b : cancels under batch-norm, unused
    const float* gamma = (const float*)d_in[3];
    const float* beta  = (const float*)d_in[4];
    const int*   idx   = (const int*)d_in[5];

    char* ws = (char*)d_ws;
    __hip_bfloat16* xb   = (__hip_bfloat16*)(ws + OFF_XB);
    __hip_bfloat16* wf   = (__hip_bfloat16*)(ws + OFF_WF);
    float*          gacc = (float*)(ws + OFF_ACC);
    float*          ss   = (float*)(ws + OFF_SS);
    __hip_bfloat16* y    = (__hip_bfloat16*)(ws + OFF_Y);
    float*          out  = (float*)d_out;

    k_cvt_x<<<NROWS * CIN / (4 * 256), 256, 0, stream>>>((const float4*)x, (ushort4*)xb);
    k_repack_w<<<KVOL, 256, 0, stream>>>(W, wf, gacc);
    k_gemm<<<NROWS / 256, 256, 0, stream>>>(xb, wf, idx, y, gacc);
    k_stats<<<1, 64, 0, stream>>>(gacc, gamma, beta, ss);
    k_apply<<<2048, 256, 0, stream>>>((const uint4*)y, ss, out);
}

// Round 2
// 237.101 us; speedup vs baseline: 1.1891x; 1.1891x over previous
//
#include <hip/hip_runtime.h>
#include <hip/hip_bf16.h>

// Problem constants (fixed by the reference)
#define NROWS 262144
#define KVOL  27
#define CIN   32
#define COUT  64
#define BN_EPS 1e-5f

using bf16x8 = __attribute__((ext_vector_type(8))) short;  // 8 bf16 = 4 VGPRs (MFMA A/B frag)
using f32x4  = __attribute__((ext_vector_type(4))) float;  // MFMA C/D frag

// ---- workspace layout (bytes) ----
#define OFF_XB  0ull                                      // x bf16: 16 MiB
#define OFF_WF  (16ull<<20)                               // W frags: 110592 B
#define OFF_ACC ((16ull<<20) + (128ull<<10))              // sum[64], sumsq[64]
#define OFF_Y   (17ull<<20)                               // y bf16: 32 MiB

__device__ __forceinline__ unsigned short f2bf(float f) {
    __hip_bfloat16 h = __float2bfloat16(f);
    return __builtin_bit_cast(unsigned short, h);
}

// ---- kernel 0: merged {x f32->bf16} + {W repack} + {zero accumulators} ----
// blocks 0..8191: cvt; blocks 8192..8218: repack kk = bid-8192
__global__ void k_prep(const float4* __restrict__ x4, ushort4* __restrict__ xb4,
                       const float* __restrict__ W, __hip_bfloat16* __restrict__ wf,
                       float* __restrict__ gacc) {
    int bid = blockIdx.x, tid = threadIdx.x;
    if (bid < 8192) {
        int i = bid * 256 + tid;
        float4 v = x4[i];
        ushort4 o;
        o.x = f2bf(v.x); o.y = f2bf(v.y); o.z = f2bf(v.z); o.w = f2bf(v.w);
        xb4[i] = o;
    } else {
        int kk = bid - 8192;            // 0..26
        int t = tid >> 6, l = tid & 63;
        int c0 = (l >> 4) * 8;
        int co = t * 16 + (l & 15);
        // Wfrag[kk][t][lane][j] = W[kk][(lane>>4)*8+j][t*16+(lane&15)]
        __hip_bfloat16* dst = wf + ((size_t)(kk * 4 + t) * 64 + l) * 8;
        #pragma unroll
        for (int j = 0; j < 8; ++j)
            dst[j] = __float2bfloat16(W[(size_t)(kk * CIN + c0 + j) * COUT + co]);
        if (kk == 0 && tid < 128) gacc[tid] = 0.0f;   // ws is poisoned 0xAA
    }
}

// ---- kernel 1: gather + MFMA GEMM -> y(bf16), per-channel sum/sumsq ----
// Block = 256 thr = 4 waves; block owns 128 rows; wave owns 32 rows x 64 cols.
// idx staged in LDS (keeps idx reads out of the vmcnt FIFO); A-gathers triple-
// buffered so b-load waits are counted vmcnt, not drains.
__global__ void __launch_bounds__(256, 5)
k_gemm(const __hip_bfloat16* __restrict__ xb, const __hip_bfloat16* __restrict__ wf,
       const int* __restrict__ idx, __hip_bfloat16* __restrict__ y,
       float* __restrict__ gacc) {
    __shared__ int s_idx[128 * KVOL];       // 13824 B
    __shared__ float ssum[4][64];
    __shared__ float ssq[4][64];

    const int tid  = threadIdx.x;
    const int w    = tid >> 6;
    const int l    = tid & 63;
    const int lrow = l & 15;      // A row / D col within frag
    const int lk8  = l >> 4;      // k-group (A/B) and row-group (D)
    const int wrb  = w * 32;                       // wave row base within block
    const int rb   = blockIdx.x * 128 + wrb;       // global row base

    // stage this block's idx rows: 128*27 ints, coalesced
    {
        const int* src = idx + (size_t)blockIdx.x * 128 * KVOL;
        for (int i = tid; i < 128 * KVOL; i += 256) s_idx[i] = src[i];
    }
    __syncthreads();

    f32x4 acc[2][4] = {};
    const bf16x8* wf8 = (const bf16x8*)wf;
    const int koff = lk8 * 8;   // element offset of this lane's 16B within a row

#define LOADID(dst, KK) { dst##0 = s_idx[(wrb + lrow) * KVOL + (KK)]; \
                          dst##1 = s_idx[(wrb + 16 + lrow) * KVOL + (KK)]; }
#define GATHER(a, dst)  { a[0] = *(const bf16x8*)(xb + (unsigned)(dst##0 * CIN) + koff); \
                          a[1] = *(const bf16x8*)(xb + (unsigned)(dst##1 * CIN) + koff); }
#define LOADB(b, KK)    { _Pragma("unroll") for (int t = 0; t < 4; ++t) \
                            b[t] = wf8[((KK) * 4 + t) * 64 + l]; }
#define MFMA8(a, b)     { _Pragma("unroll") for (int m = 0; m < 2; ++m) \
                          _Pragma("unroll") for (int t = 0; t < 4; ++t) \
                            acc[m][t] = __builtin_amdgcn_mfma_f32_16x16x32_bf16(a[m], b[t], acc[m][t], 0, 0, 0); }

    bf16x8 aA[2], aB[2], aC[2];
    int id_0, id_1;

    LOADID(id_, 0); GATHER(aA, id_);
    LOADID(id_, 1); GATHER(aB, id_);

    #pragma unroll
    for (int j = 0; j < 8; ++j) {
        const int kk = j * 3;
        bf16x8 b0[4], b1[4], b2[4];
        LOADB(b0, kk);     LOADID(id_, kk + 2); GATHER(aC, id_); MFMA8(aA, b0);
        LOADB(b1, kk + 1); LOADID(id_, kk + 3); GATHER(aA, id_); MFMA8(aB, b1);
        LOADB(b2, kk + 2); LOADID(id_, kk + 4); GATHER(aB, id_); MFMA8(aC, b2);
    }
    {   // tail: kk = 24,25,26 ; aA=24, aB=25 in flight
        bf16x8 b0[4], b1[4], b2[4];
        LOADB(b0, 24); LOADID(id_, 26); GATHER(aC, id_); MFMA8(aA, b0);
        LOADB(b1, 25); MFMA8(aB, b1);
        LOADB(b2, 26); MFMA8(aC, b2);
    }
#undef LOADID
#undef GATHER
#undef LOADB
#undef MFMA8

    // epilogue: store y (bf16) + per-channel sums
    float s[4] = {0, 0, 0, 0}, sq[4] = {0, 0, 0, 0};
    #pragma unroll
    for (int m = 0; m < 2; ++m) {
        #pragma unroll
        for (int r = 0; r < 4; ++r) {
            int row = rb + m * 16 + lk8 * 4 + r;   // D: row=(l>>4)*4+reg, col=l&15
            #pragma unroll
            for (int t = 0; t < 4; ++t) {
                float v = acc[m][t][r];
                y[(size_t)row * COUT + t * 16 + lrow] = __float2bfloat16(v);
                s[t] += v;
                sq[t] += v * v;
            }
        }
    }
    #pragma unroll
    for (int t = 0; t < 4; ++t) {
        s[t]  += __shfl_xor(s[t], 16, 64);  s[t]  += __shfl_xor(s[t], 32, 64);
        sq[t] += __shfl_xor(sq[t], 16, 64); sq[t] += __shfl_xor(sq[t], 32, 64);
    }
    if (l < 16) {
        #pragma unroll
        for (int t = 0; t < 4; ++t) { ssum[w][t * 16 + l] = s[t]; ssq[w][t * 16 + l] = sq[t]; }
    }
    __syncthreads();
    if (tid < 64) {
        float ts = 0, tq = 0;
        #pragma unroll
        for (int ww = 0; ww < 4; ++ww) { ts += ssum[ww][tid]; tq += ssq[ww][tid]; }
        atomicAdd(&gacc[tid], ts);
        atomicAdd(&gacc[64 + tid], tq);
    }
}

// ---- kernel 2: stats (redundant per block, trivial) + out = relu(y*sc+sh) ----
__global__ void k_apply(const uint4* __restrict__ y8, const float* __restrict__ gacc,
                        const float* __restrict__ gamma, const float* __restrict__ beta,
                        float* __restrict__ out) {
    __shared__ float s_sc[64], s_sh[64];
    const int tid = threadIdx.x;
    if (tid < 64) {
        float inv_n = 1.0f / (float)NROWS;
        float mean = gacc[tid] * inv_n;
        float var  = gacc[64 + tid] * inv_n - mean * mean;
        float rstd = rsqrtf(var + BN_EPS);
        float sc = gamma[tid] * rstd;
        s_sc[tid] = sc;
        s_sh[tid] = beta[tid] - mean * sc;
    }
    __syncthreads();

    const int nchunk = NROWS * COUT / 8;
    int i0 = blockIdx.x * blockDim.x + tid;
    int c0 = (i0 * 8) & 63;   // thread stride * 8 is a multiple of 64 -> fixed cols
    float sc[8], sh[8];
    #pragma unroll
    for (int j = 0; j < 8; ++j) { sc[j] = s_sc[c0 + j]; sh[j] = s_sh[c0 + j]; }
    for (int i = i0; i < nchunk; i += gridDim.x * blockDim.x) {
        uint4 v = y8[i];
        const unsigned short* p = (const unsigned short*)&v;
        float r[8];
        #pragma unroll
        for (int j = 0; j < 8; ++j) {
            float f = __uint_as_float((unsigned)p[j] << 16);
            r[j] = fmaxf(0.0f, f * sc[j] + sh[j]);
        }
        float4* o = (float4*)(out + (size_t)i * 8);
        o[0] = make_float4(r[0], r[1], r[2], r[3]);
        o[1] = make_float4(r[4], r[5], r[6], r[7]);
    }
}

extern "C" void kernel_launch(void* const* d_in, const int* in_sizes, int n_in,
                              void* d_out, int out_size, void* d_ws, size_t ws_size,
                              hipStream_t stream) {
    const float* x     = (const float*)d_in[0];
    const float* W     = (const float*)d_in[1];
    // d_in[2] = b : cancels under batch-norm, unused
    const float* gamma = (const float*)d_in[3];
    const float* beta  = (const float*)d_in[4];
    const int*   idx   = (const int*)d_in[5];

    char* ws = (char*)d_ws;
    __hip_bfloat16* xb   = (__hip_bfloat16*)(ws + OFF_XB);
    __hip_bfloat16* wf   = (__hip_bfloat16*)(ws + OFF_WF);
    float*          gacc = (float*)(ws + OFF_ACC);
    __hip_bfloat16* y    = (__hip_bfloat16*)(ws + OFF_Y);
    float*          out  = (float*)d_out;

    k_prep<<<8192 + KVOL, 256, 0, stream>>>((const float4*)x, (ushort4*)xb, W, wf, gacc);
    k_gemm<<<NROWS / 128, 256, 0, stream>>>(xb, wf, idx, y, gacc);
    k_apply<<<2048, 256, 0, stream>>>((const uint4*)y, gacc, gamma, beta, out);
}